// Round 4
// baseline (401.651 us; speedup 1.0000x reference)
//
#include <hip/hip_runtime.h>
#include <cstddef>

#define THREADS 256

// ---------------------------------------------------------------------------
// GEMM: out[N,128] = A[N,128] @ W[128,128], f32. Used only for W^2, W^3 (tiny).
// ---------------------------------------------------------------------------
__global__ __launch_bounds__(256, 2)
void gemm128_kernel(const float* __restrict__ A, const float* __restrict__ W,
                    float* __restrict__ out, int N) {
    __shared__ float Ws[128 * 128];
    __shared__ float Xs[32 * 128];
    const int tid = threadIdx.x;

    const float4* __restrict__ W4 = (const float4*)W;
    float4* Ws4 = (float4*)Ws;
#pragma unroll
    for (int i = 0; i < 16; ++i) Ws4[tid + i * 256] = W4[tid + i * 256];

    const int row0 = blockIdx.x * 32;
    const float4* __restrict__ A4 = (const float4*)A;
    float4* Xs4 = (float4*)Xs;
#pragma unroll
    for (int i = 0; i < 4; ++i) {
        int li = tid + i * 256;
        int r = row0 + (li >> 5);
        float4 v = {0.f, 0.f, 0.f, 0.f};
        if (r < N) v = A4[(size_t)r * 32 + (li & 31)];
        Xs4[li] = v;
    }
    __syncthreads();

    const int c4 = tid & 31;
    const int rb = (tid >> 5) * 4;
    float4 a0 = {0.f, 0.f, 0.f, 0.f};
    float4 a1 = {0.f, 0.f, 0.f, 0.f};
    float4 a2 = {0.f, 0.f, 0.f, 0.f};
    float4 a3 = {0.f, 0.f, 0.f, 0.f};
    const float* x0p = &Xs[(rb + 0) * 128];
    const float* x1p = &Xs[(rb + 1) * 128];
    const float* x2p = &Xs[(rb + 2) * 128];
    const float* x3p = &Xs[(rb + 3) * 128];

#pragma unroll 8
    for (int k = 0; k < 128; ++k) {
        float4 wv = Ws4[k * 32 + c4];
        float x0 = x0p[k];
        float x1 = x1p[k];
        float x2 = x2p[k];
        float x3 = x3p[k];
        a0.x = fmaf(x0, wv.x, a0.x); a0.y = fmaf(x0, wv.y, a0.y);
        a0.z = fmaf(x0, wv.z, a0.z); a0.w = fmaf(x0, wv.w, a0.w);
        a1.x = fmaf(x1, wv.x, a1.x); a1.y = fmaf(x1, wv.y, a1.y);
        a1.z = fmaf(x1, wv.z, a1.z); a1.w = fmaf(x1, wv.w, a1.w);
        a2.x = fmaf(x2, wv.x, a2.x); a2.y = fmaf(x2, wv.y, a2.y);
        a2.z = fmaf(x2, wv.z, a2.z); a2.w = fmaf(x2, wv.w, a2.w);
        a3.x = fmaf(x3, wv.x, a3.x); a3.y = fmaf(x3, wv.y, a3.y);
        a3.z = fmaf(x3, wv.z, a3.z); a3.w = fmaf(x3, wv.w, a3.w);
    }

    float4* out4 = (float4*)out;
    const int r = row0 + rb;
    if (r + 3 < N) {
        out4[(size_t)(r + 0) * 32 + c4] = a0;
        out4[(size_t)(r + 1) * 32 + c4] = a1;
        out4[(size_t)(r + 2) * 32 + c4] = a2;
        out4[(size_t)(r + 3) * 32 + c4] = a3;
    } else {
        if (r + 0 < N) out4[(size_t)(r + 0) * 32 + c4] = a0;
        if (r + 1 < N) out4[(size_t)(r + 1) * 32 + c4] = a1;
        if (r + 2 < N) out4[(size_t)(r + 2) * 32 + c4] = a2;
        if (r + 3 < N) out4[(size_t)(r + 3) * 32 + c4] = a3;
    }
}

// ---------------------------------------------------------------------------
// Dual GEMM: out = A1 @ Wa - A2 @ Wb.
// W-only LDS (64KB -> 2 blocks/CU, 16 waves). X streamed from global via
// half-wave-broadcast float4 loads (lanes of a c4-group share the address).
// 512 threads, 64 rows/block, thread = 4 rows x 1 float4-col.
// ---------------------------------------------------------------------------
__device__ __forceinline__ void rowfma(float4& acc, const float4 xv,
                                       const float4 w0, const float4 w1,
                                       const float4 w2, const float4 w3) {
    acc.x = fmaf(xv.x, w0.x, acc.x); acc.y = fmaf(xv.x, w0.y, acc.y);
    acc.z = fmaf(xv.x, w0.z, acc.z); acc.w = fmaf(xv.x, w0.w, acc.w);
    acc.x = fmaf(xv.y, w1.x, acc.x); acc.y = fmaf(xv.y, w1.y, acc.y);
    acc.z = fmaf(xv.y, w1.z, acc.z); acc.w = fmaf(xv.y, w1.w, acc.w);
    acc.x = fmaf(xv.z, w2.x, acc.x); acc.y = fmaf(xv.z, w2.y, acc.y);
    acc.z = fmaf(xv.z, w2.z, acc.z); acc.w = fmaf(xv.z, w2.w, acc.w);
    acc.x = fmaf(xv.w, w3.x, acc.x); acc.y = fmaf(xv.w, w3.y, acc.y);
    acc.z = fmaf(xv.w, w3.z, acc.z); acc.w = fmaf(xv.w, w3.w, acc.w);
}

__global__ __launch_bounds__(512, 4)
void gemm_dual_kernel(const float* __restrict__ A1, const float* __restrict__ Wa,
                      const float* __restrict__ A2, const float* __restrict__ Wb,
                      float* __restrict__ out, int N) {
    __shared__ float4 Ws4[128 * 32];  // 64KB
    const int tid = threadIdx.x;
    const int row0 = blockIdx.x * 64;
    const int c4 = tid & 31;
    const int rb = (tid >> 5) * 4;  // 0..60

    float4 a0 = {0.f, 0.f, 0.f, 0.f};
    float4 a1 = {0.f, 0.f, 0.f, 0.f};
    float4 a2 = {0.f, 0.f, 0.f, 0.f};
    float4 a3 = {0.f, 0.f, 0.f, 0.f};

    const int r = row0 + rb;
    const int rc0 = (r + 0 < N) ? r + 0 : N - 1;
    const int rc1 = (r + 1 < N) ? r + 1 : N - 1;
    const int rc2 = (r + 2 < N) ? r + 2 : N - 1;
    const int rc3 = (r + 3 < N) ? r + 3 : N - 1;

    for (int pass = 0; pass < 2; ++pass) {
        const float4* __restrict__ Wsrc = (const float4*)(pass ? Wb : Wa);
        const float4* __restrict__ Asrc = (const float4*)(pass ? A2 : A1);
        if (pass) __syncthreads();  // pass-0 readers done before restage
#pragma unroll
        for (int i = 0; i < 8; ++i) {
            float4 v = Wsrc[tid + i * 512];
            if (pass) { v.x = -v.x; v.y = -v.y; v.z = -v.z; v.w = -v.w; }
            Ws4[tid + i * 512] = v;
        }
        __syncthreads();

        const float4* __restrict__ xp0 = Asrc + (size_t)rc0 * 32;
        const float4* __restrict__ xp1 = Asrc + (size_t)rc1 * 32;
        const float4* __restrict__ xp2 = Asrc + (size_t)rc2 * 32;
        const float4* __restrict__ xp3 = Asrc + (size_t)rc3 * 32;

#pragma unroll 4
        for (int kq = 0; kq < 32; ++kq) {
            float4 w0 = Ws4[(4 * kq + 0) * 32 + c4];
            float4 w1 = Ws4[(4 * kq + 1) * 32 + c4];
            float4 w2 = Ws4[(4 * kq + 2) * 32 + c4];
            float4 w3 = Ws4[(4 * kq + 3) * 32 + c4];
            float4 xv0 = xp0[kq];
            float4 xv1 = xp1[kq];
            float4 xv2 = xp2[kq];
            float4 xv3 = xp3[kq];
            rowfma(a0, xv0, w0, w1, w2, w3);
            rowfma(a1, xv1, w0, w1, w2, w3);
            rowfma(a2, xv2, w0, w1, w2, w3);
            rowfma(a3, xv3, w0, w1, w2, w3);
        }
    }

    float4* out4 = (float4*)out;
    if (r + 3 < N) {
        out4[(size_t)(r + 0) * 32 + c4] = a0;
        out4[(size_t)(r + 1) * 32 + c4] = a1;
        out4[(size_t)(r + 2) * 32 + c4] = a2;
        out4[(size_t)(r + 3) * 32 + c4] = a3;
    } else {
        if (r + 0 < N) out4[(size_t)(r + 0) * 32 + c4] = a0;
        if (r + 1 < N) out4[(size_t)(r + 1) * 32 + c4] = a1;
        if (r + 2 < N) out4[(size_t)(r + 2) * 32 + c4] = a2;
        if (r + 3 < N) out4[(size_t)(r + 3) * 32 + c4] = a3;
    }
}

// ---------------------------------------------------------------------------
// CSR build: histogram -> single-block scan -> scatter
// ---------------------------------------------------------------------------
__global__ void hist_kernel(const int* __restrict__ erows, int* __restrict__ counts, int E) {
    int e = blockIdx.x * blockDim.x + threadIdx.x;
    if (e < E) atomicAdd(&counts[erows[e]], 1);
}

// One block, 1024 threads; each thread owns a contiguous chunk.
__global__ __launch_bounds__(1024)
void scan_kernel(const int* __restrict__ counts, int* __restrict__ rowptr,
                 int* __restrict__ cursor, int n) {
    __shared__ int sums[1024];
    const int tid = threadIdx.x;
    const int items = (n + 1023) >> 10;
    const int start = tid * items;
    const int end = (start + items < n) ? start + items : n;
    int s = 0;
    for (int i = start; i < end; ++i) s += counts[i];
    sums[tid] = s;
    __syncthreads();
#pragma unroll
    for (int off = 1; off < 1024; off <<= 1) {
        int t = (tid >= off) ? sums[tid - off] : 0;
        __syncthreads();
        sums[tid] += t;
        __syncthreads();
    }
    int run = sums[tid] - s;  // exclusive prefix for this chunk
    for (int i = start; i < end; ++i) {
        run += counts[i];
        rowptr[i + 1] = run;
        cursor[i + 1] = run;
    }
    if (tid == 0) { rowptr[0] = 0; cursor[0] = 0; }
}

__global__ void scatter_kernel(const int* __restrict__ erows, const int* __restrict__ ecols,
                               const float* __restrict__ evals, int* __restrict__ cursor,
                               int2* __restrict__ csr, int E) {
    int e = blockIdx.x * blockDim.x + threadIdx.x;
    if (e < E) {
        int r = erows[e];
        int pos = atomicAdd(&cursor[r], 1);
        int2 p;
        p.x = ecols[e];
        p.y = __float_as_int(2.0f * evals[e]);
        csr[pos] = p;
    }
}

// ---------------------------------------------------------------------------
// Gather SpMM: S[row] = sum_e 2*val_e * X[col_e]  (-  init[row] if init)
// 32 lanes per row, float4 per lane, 8-edge unrolled, dual accumulators.
// ---------------------------------------------------------------------------
__global__ void spmm_gather_kernel(const int* __restrict__ rowptr, const int2* __restrict__ csr,
                                   const float* __restrict__ X, const float* __restrict__ init,
                                   float* __restrict__ S, int N) {
    long long idx = (long long)blockIdx.x * blockDim.x + threadIdx.x;
    int row = (int)(idx >> 5);
    if (row >= N) return;
    int lane = (int)(idx & 31);
    const float4* __restrict__ X4 = (const float4*)X;
    float4 accA = {0.f, 0.f, 0.f, 0.f};
    float4 accB = {0.f, 0.f, 0.f, 0.f};
    if (init) {
        float4 t = ((const float4*)init)[(size_t)row * 32 + lane];
        accA.x = -t.x; accA.y = -t.y; accA.z = -t.z; accA.w = -t.w;
    }
    int p = rowptr[row];
    const int p1 = rowptr[row + 1];
    for (; p + 7 < p1; p += 8) {
        int2 cv0 = csr[p + 0];
        int2 cv1 = csr[p + 1];
        int2 cv2 = csr[p + 2];
        int2 cv3 = csr[p + 3];
        int2 cv4 = csr[p + 4];
        int2 cv5 = csr[p + 5];
        int2 cv6 = csr[p + 6];
        int2 cv7 = csr[p + 7];
        float4 x0 = X4[(size_t)cv0.x * 32 + lane];
        float4 x1 = X4[(size_t)cv1.x * 32 + lane];
        float4 x2 = X4[(size_t)cv2.x * 32 + lane];
        float4 x3 = X4[(size_t)cv3.x * 32 + lane];
        float4 x4 = X4[(size_t)cv4.x * 32 + lane];
        float4 x5 = X4[(size_t)cv5.x * 32 + lane];
        float4 x6 = X4[(size_t)cv6.x * 32 + lane];
        float4 x7 = X4[(size_t)cv7.x * 32 + lane];
        float v0 = __int_as_float(cv0.y);
        float v1 = __int_as_float(cv1.y);
        float v2 = __int_as_float(cv2.y);
        float v3 = __int_as_float(cv3.y);
        float v4 = __int_as_float(cv4.y);
        float v5 = __int_as_float(cv5.y);
        float v6 = __int_as_float(cv6.y);
        float v7 = __int_as_float(cv7.y);
        accA.x = fmaf(v0, x0.x, accA.x); accA.y = fmaf(v0, x0.y, accA.y);
        accA.z = fmaf(v0, x0.z, accA.z); accA.w = fmaf(v0, x0.w, accA.w);
        accB.x = fmaf(v1, x1.x, accB.x); accB.y = fmaf(v1, x1.y, accB.y);
        accB.z = fmaf(v1, x1.z, accB.z); accB.w = fmaf(v1, x1.w, accB.w);
        accA.x = fmaf(v2, x2.x, accA.x); accA.y = fmaf(v2, x2.y, accA.y);
        accA.z = fmaf(v2, x2.z, accA.z); accA.w = fmaf(v2, x2.w, accA.w);
        accB.x = fmaf(v3, x3.x, accB.x); accB.y = fmaf(v3, x3.y, accB.y);
        accB.z = fmaf(v3, x3.z, accB.z); accB.w = fmaf(v3, x3.w, accB.w);
        accA.x = fmaf(v4, x4.x, accA.x); accA.y = fmaf(v4, x4.y, accA.y);
        accA.z = fmaf(v4, x4.z, accA.z); accA.w = fmaf(v4, x4.w, accA.w);
        accB.x = fmaf(v5, x5.x, accB.x); accB.y = fmaf(v5, x5.y, accB.y);
        accB.z = fmaf(v5, x5.z, accB.z); accB.w = fmaf(v5, x5.w, accB.w);
        accA.x = fmaf(v6, x6.x, accA.x); accA.y = fmaf(v6, x6.y, accA.y);
        accA.z = fmaf(v6, x6.z, accA.z); accA.w = fmaf(v6, x6.w, accA.w);
        accB.x = fmaf(v7, x7.x, accB.x); accB.y = fmaf(v7, x7.y, accB.y);
        accB.z = fmaf(v7, x7.z, accB.z); accB.w = fmaf(v7, x7.w, accB.w);
    }
    for (; p + 3 < p1; p += 4) {
        int2 cv0 = csr[p + 0];
        int2 cv1 = csr[p + 1];
        int2 cv2 = csr[p + 2];
        int2 cv3 = csr[p + 3];
        float4 x0 = X4[(size_t)cv0.x * 32 + lane];
        float4 x1 = X4[(size_t)cv1.x * 32 + lane];
        float4 x2 = X4[(size_t)cv2.x * 32 + lane];
        float4 x3 = X4[(size_t)cv3.x * 32 + lane];
        float v0 = __int_as_float(cv0.y);
        float v1 = __int_as_float(cv1.y);
        float v2 = __int_as_float(cv2.y);
        float v3 = __int_as_float(cv3.y);
        accA.x = fmaf(v0, x0.x, accA.x); accA.y = fmaf(v0, x0.y, accA.y);
        accA.z = fmaf(v0, x0.z, accA.z); accA.w = fmaf(v0, x0.w, accA.w);
        accB.x = fmaf(v1, x1.x, accB.x); accB.y = fmaf(v1, x1.y, accB.y);
        accB.z = fmaf(v1, x1.z, accB.z); accB.w = fmaf(v1, x1.w, accB.w);
        accA.x = fmaf(v2, x2.x, accA.x); accA.y = fmaf(v2, x2.y, accA.y);
        accA.z = fmaf(v2, x2.z, accA.z); accA.w = fmaf(v2, x2.w, accA.w);
        accB.x = fmaf(v3, x3.x, accB.x); accB.y = fmaf(v3, x3.y, accB.y);
        accB.z = fmaf(v3, x3.z, accB.z); accB.w = fmaf(v3, x3.w, accB.w);
    }
    for (; p < p1; ++p) {
        int2 cv = csr[p];
        float v = __int_as_float(cv.y);
        float4 x = X4[(size_t)cv.x * 32 + lane];
        accA.x = fmaf(v, x.x, accA.x);
        accA.y = fmaf(v, x.y, accA.y);
        accA.z = fmaf(v, x.z, accA.z);
        accA.w = fmaf(v, x.w, accA.w);
    }
    float4 acc;
    acc.x = accA.x + accB.x;
    acc.y = accA.y + accB.y;
    acc.z = accA.z + accB.z;
    acc.w = accA.w + accB.w;
    ((float4*)S)[(size_t)row * 32 + lane] = acc;
}

extern "C" void kernel_launch(void* const* d_in, const int* in_sizes, int n_in,
                              void* d_out, int out_size, void* d_ws, size_t ws_size,
                              hipStream_t stream) {
    const float* X     = (const float*)d_in[0];
    const int*   erows = (const int*)d_in[1];
    const int*   ecols = (const int*)d_in[2];
    const float* evals = (const float*)d_in[3];
    const float* W     = (const float*)d_in[4];
    float* out = (float*)d_out;

    const int N = in_sizes[0] / 128;  // 50000
    const int E = in_sizes[1];        // 800000

    // Workspace layout (4-byte elems; csr kept 8B-aligned)
    float* t2     = (float*)d_ws;                      // T2 = 2A.X - X   (N*128)
    float* u2     = t2 + (size_t)N * 128;              // U2 = 2A.T2      (N*128)
    float* W2     = u2 + (size_t)N * 128;              // 128*128
    float* W3     = W2 + 16384;                        // 128*128
    int2*  csr    = (int2*)(W3 + 16384);               // E int2 (8B-aligned)
    int*   rowptr = (int*)(csr + E);                   // N+1
    int*   cursor = rowptr + (N + 1);                  // N+1
    int*   counts = cursor + (N + 1);                  // N

    const int e_blocks = (E + 255) / 256;
    const int g_blocks = (int)(((long long)N * 32 + 255) / 256);
    const int d_blocks = (N + 63) / 64;

    // --- W powers (tiny) ---
    gemm128_kernel<<<4, THREADS, 0, stream>>>(W, W, W2, 128);   // W2 = W@W
    gemm128_kernel<<<4, THREADS, 0, stream>>>(W2, W, W3, 128);  // W3 = W2@W

    // --- CSR build ---
    hipMemsetAsync(counts, 0, (size_t)N * sizeof(int), stream);
    hist_kernel<<<e_blocks, THREADS, 0, stream>>>(erows, counts, E);
    scan_kernel<<<1, 1024, 0, stream>>>(counts, rowptr, cursor, N);
    scatter_kernel<<<e_blocks, THREADS, 0, stream>>>(erows, ecols, evals, cursor, csr, E);

    // --- Chebyshev chain (reassociated) ---
    // T2 = 2A.X - X
    spmm_gather_kernel<<<g_blocks, THREADS, 0, stream>>>(rowptr, csr, X, X, t2, N);
    // U2 = 2A.T2
    spmm_gather_kernel<<<g_blocks, THREADS, 0, stream>>>(rowptr, csr, t2, nullptr, u2, N);
    // out = U2@W3 - X@W2
    gemm_dual_kernel<<<d_blocks, 512, 0, stream>>>(u2, W3, X, W2, out, N);
}

// Round 5
// 279.071 us; speedup vs baseline: 1.4392x; 1.4392x over previous
//
#include <hip/hip_runtime.h>
#include <cstddef>
#include <cstdint>

#define THREADS 256

#define GLOBAL_AS __attribute__((address_space(1)))
#define LDS_AS    __attribute__((address_space(3)))

// Async global->LDS DMA, 16B per lane. LDS dest must be linear in lane order.
__device__ __forceinline__ void async_copy16(const void* g, void* l) {
    __builtin_amdgcn_global_load_lds((const GLOBAL_AS void*)g, (LDS_AS void*)l, 16, 0, 0);
}

// ---------------------------------------------------------------------------
// Shared inner product: 32-row x 128-col tile, thread = 4 rows x 1 float4-col.
// ---------------------------------------------------------------------------
__device__ __forceinline__ void rowfma(float4& acc, const float4 xv,
                                       const float4 w0, const float4 w1,
                                       const float4 w2, const float4 w3) {
    acc.x = fmaf(xv.x, w0.x, acc.x); acc.y = fmaf(xv.x, w0.y, acc.y);
    acc.z = fmaf(xv.x, w0.z, acc.z); acc.w = fmaf(xv.x, w0.w, acc.w);
    acc.x = fmaf(xv.y, w1.x, acc.x); acc.y = fmaf(xv.y, w1.y, acc.y);
    acc.z = fmaf(xv.y, w1.z, acc.z); acc.w = fmaf(xv.y, w1.w, acc.w);
    acc.x = fmaf(xv.z, w2.x, acc.x); acc.y = fmaf(xv.z, w2.y, acc.y);
    acc.z = fmaf(xv.z, w2.z, acc.z); acc.w = fmaf(xv.z, w2.w, acc.w);
    acc.x = fmaf(xv.w, w3.x, acc.x); acc.y = fmaf(xv.w, w3.y, acc.y);
    acc.z = fmaf(xv.w, w3.z, acc.z); acc.w = fmaf(xv.w, w3.w, acc.w);
}

template <bool NEG>
__device__ __forceinline__ void mm32(const float4* Ws4, const float4* Xs4,
                                     int c4, int rb,
                                     float4& a0, float4& a1, float4& a2, float4& a3) {
#pragma unroll 4
    for (int kq = 0; kq < 32; ++kq) {
        float4 w0 = Ws4[(4 * kq + 0) * 32 + c4];
        float4 w1 = Ws4[(4 * kq + 1) * 32 + c4];
        float4 w2 = Ws4[(4 * kq + 2) * 32 + c4];
        float4 w3 = Ws4[(4 * kq + 3) * 32 + c4];
        float4 x0 = Xs4[(rb + 0) * 32 + kq];
        float4 x1 = Xs4[(rb + 1) * 32 + kq];
        float4 x2 = Xs4[(rb + 2) * 32 + kq];
        float4 x3 = Xs4[(rb + 3) * 32 + kq];
        if (NEG) {  // folds into FMA src modifiers (free)
            x0.x = -x0.x; x0.y = -x0.y; x0.z = -x0.z; x0.w = -x0.w;
            x1.x = -x1.x; x1.y = -x1.y; x1.z = -x1.z; x1.w = -x1.w;
            x2.x = -x2.x; x2.y = -x2.y; x2.z = -x2.z; x2.w = -x2.w;
            x3.x = -x3.x; x3.y = -x3.y; x3.z = -x3.z; x3.w = -x3.w;
        }
        rowfma(a0, x0, w0, w1, w2, w3);
        rowfma(a1, x1, w0, w1, w2, w3);
        rowfma(a2, x2, w0, w1, w2, w3);
        rowfma(a3, x3, w0, w1, w2, w3);
    }
}

// ---------------------------------------------------------------------------
// W powers in ONE launch: blocks 0-3 -> W2 = W@W slices; blocks 4-7 -> W3
// slices computed as (W[slice]@W)@W (no cross-block dependency).
// ---------------------------------------------------------------------------
__global__ __launch_bounds__(256, 2)
void wpow_kernel(const float* __restrict__ W, float* __restrict__ W2,
                 float* __restrict__ W3) {
    __shared__ float4 Ws4[128 * 32];  // 64KB: full W
    __shared__ float4 Xs4[32 * 32];   // 16KB: 32-row operand slice
    const int tid = threadIdx.x;
    const int row0 = (blockIdx.x & 3) * 32;
    const bool is3 = blockIdx.x >= 4;
    const float4* __restrict__ W4 = (const float4*)W;

#pragma unroll
    for (int i = 0; i < 16; ++i) Ws4[tid + i * 256] = W4[tid + i * 256];
#pragma unroll
    for (int i = 0; i < 4; ++i) {
        int li = tid + i * 256;
        Xs4[li] = W4[(size_t)(row0 + (li >> 5)) * 32 + (li & 31)];
    }
    __syncthreads();

    const int c4 = tid & 31;
    const int rb = (tid >> 5) * 4;
    float4 a0 = {0.f, 0.f, 0.f, 0.f};
    float4 a1 = {0.f, 0.f, 0.f, 0.f};
    float4 a2 = {0.f, 0.f, 0.f, 0.f};
    float4 a3 = {0.f, 0.f, 0.f, 0.f};
    mm32<false>(Ws4, Xs4, c4, rb, a0, a1, a2, a3);

    if (is3) {  // second multiply: S2 = S1 @ W
        __syncthreads();
        Xs4[(rb + 0) * 32 + c4] = a0;
        Xs4[(rb + 1) * 32 + c4] = a1;
        Xs4[(rb + 2) * 32 + c4] = a2;
        Xs4[(rb + 3) * 32 + c4] = a3;
        __syncthreads();
        a0 = {0.f, 0.f, 0.f, 0.f};
        a1 = {0.f, 0.f, 0.f, 0.f};
        a2 = {0.f, 0.f, 0.f, 0.f};
        a3 = {0.f, 0.f, 0.f, 0.f};
        mm32<false>(Ws4, Xs4, c4, rb, a0, a1, a2, a3);
    }

    float4* dst4 = (float4*)(is3 ? W3 : W2);
    const int r = row0 + rb;
    dst4[(size_t)(r + 0) * 32 + c4] = a0;
    dst4[(size_t)(r + 1) * 32 + c4] = a1;
    dst4[(size_t)(r + 2) * 32 + c4] = a2;
    dst4[(size_t)(r + 3) * 32 + c4] = a3;
}

// ---------------------------------------------------------------------------
// Dual GEMM: out = A1 @ Wa - A2 @ Wb. R3 structure (W 64KB + Xs 16KB LDS),
// staged via async global_load_lds; pass-1 negation folded into FMA mods.
// ---------------------------------------------------------------------------
__global__ __launch_bounds__(256, 2)
void gemm_dual_kernel(const float* __restrict__ A1, const float* __restrict__ Wa,
                      const float* __restrict__ A2, const float* __restrict__ Wb,
                      float* __restrict__ out, int N) {
    __shared__ float4 Ws4[128 * 32];  // 64KB
    __shared__ float4 Xs4[32 * 32];   // 16KB
    const int tid = threadIdx.x;
    const int row0 = blockIdx.x * 32;
    const int c4 = tid & 31;
    const int rb = (tid >> 5) * 4;
    const int r = row0 + rb;

    float4 a0 = {0.f, 0.f, 0.f, 0.f};
    float4 a1 = {0.f, 0.f, 0.f, 0.f};
    float4 a2 = {0.f, 0.f, 0.f, 0.f};
    float4 a3 = {0.f, 0.f, 0.f, 0.f};

    // ---- pass 0: + A1 @ Wa ----
    {
        const float4* __restrict__ Wsrc = (const float4*)Wa;
        const float4* __restrict__ Asrc = (const float4*)A1;
#pragma unroll
        for (int i = 0; i < 16; ++i)
            async_copy16(&Wsrc[tid + i * 256], &Ws4[tid + i * 256]);
#pragma unroll
        for (int i = 0; i < 4; ++i) {
            int li = tid + i * 256;
            int rr = row0 + (li >> 5);
            if (rr >= N) rr = N - 1;  // clamp: loaded but never stored
            async_copy16(&Asrc[(size_t)rr * 32 + (li & 31)], &Xs4[li]);
        }
        __syncthreads();  // drains vmcnt before barrier
        mm32<false>(Ws4, Xs4, c4, rb, a0, a1, a2, a3);
    }
    __syncthreads();  // pass-0 readers done before restage

    // ---- pass 1: - A2 @ Wb ----
    {
        const float4* __restrict__ Wsrc = (const float4*)Wb;
        const float4* __restrict__ Asrc = (const float4*)A2;
#pragma unroll
        for (int i = 0; i < 16; ++i)
            async_copy16(&Wsrc[tid + i * 256], &Ws4[tid + i * 256]);
#pragma unroll
        for (int i = 0; i < 4; ++i) {
            int li = tid + i * 256;
            int rr = row0 + (li >> 5);
            if (rr >= N) rr = N - 1;
            async_copy16(&Asrc[(size_t)rr * 32 + (li & 31)], &Xs4[li]);
        }
        __syncthreads();
        mm32<true>(Ws4, Xs4, c4, rb, a0, a1, a2, a3);
    }

    float4* out4 = (float4*)out;
    if (r + 3 < N) {
        out4[(size_t)(r + 0) * 32 + c4] = a0;
        out4[(size_t)(r + 1) * 32 + c4] = a1;
        out4[(size_t)(r + 2) * 32 + c4] = a2;
        out4[(size_t)(r + 3) * 32 + c4] = a3;
    } else {
        if (r + 0 < N) out4[(size_t)(r + 0) * 32 + c4] = a0;
        if (r + 1 < N) out4[(size_t)(r + 1) * 32 + c4] = a1;
        if (r + 2 < N) out4[(size_t)(r + 2) * 32 + c4] = a2;
        if (r + 3 < N) out4[(size_t)(r + 3) * 32 + c4] = a3;
    }
}

// ---------------------------------------------------------------------------
// CSR build: histogram -> scanA (multi-block) -> scanBC (fused) -> scatter
// ---------------------------------------------------------------------------
__global__ void hist_kernel(const int* __restrict__ erows, int* __restrict__ counts, int E) {
    int e = blockIdx.x * blockDim.x + threadIdx.x;
    if (e < E) atomicAdd(&counts[erows[e]], 1);
}

__global__ __launch_bounds__(1024)
void scanA_kernel(const int* __restrict__ counts, int* __restrict__ rowptr,
                  int* __restrict__ blocksum, int n) {
    __shared__ int buf[1024];
    const int tid = threadIdx.x;
    const int i = blockIdx.x * 1024 + tid;
    int v = (i < n) ? counts[i] : 0;
    buf[tid] = v;
    __syncthreads();
#pragma unroll
    for (int off = 1; off < 1024; off <<= 1) {
        int t = (tid >= off) ? buf[tid - off] : 0;
        __syncthreads();
        buf[tid] += t;
        __syncthreads();
    }
    if (i < n) rowptr[i + 1] = buf[tid];
    if (tid == 1023) blocksum[blockIdx.x] = buf[1023];
}

// Fused: every block's wave 0 shfl-scans the (<=64) raw block sums, then all
// threads add their chunk offset. Replaces scanB+scanC.
__global__ void scanBC_kernel(int* __restrict__ rowptr, int* __restrict__ cursor,
                              const int* __restrict__ blocksum, int n, int nb) {
    __shared__ int off[64];
    const int tid = threadIdx.x;
    if (tid < 64) {
        int v = (tid < nb) ? blocksum[tid] : 0;
        int orig = v;
#pragma unroll
        for (int o = 1; o < 64; o <<= 1) {
            int t = __shfl_up(v, o);
            if (tid >= o) v += t;
        }
        off[tid] = v - orig;  // exclusive prefix
    }
    __syncthreads();
    int i = blockIdx.x * blockDim.x + tid;
    if (i < n) {
        int v = rowptr[i + 1] + off[i >> 10];
        rowptr[i + 1] = v;
        cursor[i + 1] = v;
    }
    if (i == 0) { rowptr[0] = 0; cursor[0] = 0; }
}

__global__ void scatter_kernel(const int* __restrict__ erows, const int* __restrict__ ecols,
                               const float* __restrict__ evals, int* __restrict__ cursor,
                               int2* __restrict__ csr, int E) {
    int e = blockIdx.x * blockDim.x + threadIdx.x;
    if (e < E) {
        int r = erows[e];
        int pos = atomicAdd(&cursor[r], 1);
        int2 p;
        p.x = ecols[e];
        p.y = __float_as_int(2.0f * evals[e]);
        csr[pos] = p;
    }
}

// ---------------------------------------------------------------------------
// Gather SpMM: S[row] = sum_e 2*val_e * X[col_e]  (- init[row] if init)
// 32 lanes per row, float4 per lane, 8-edge unrolled, dual accumulators.
// ---------------------------------------------------------------------------
__global__ void spmm_gather_kernel(const int* __restrict__ rowptr, const int2* __restrict__ csr,
                                   const float* __restrict__ X, const float* __restrict__ init,
                                   float* __restrict__ S, int N) {
    long long idx = (long long)blockIdx.x * blockDim.x + threadIdx.x;
    int row = (int)(idx >> 5);
    if (row >= N) return;
    int lane = (int)(idx & 31);
    const float4* __restrict__ X4 = (const float4*)X;
    float4 accA = {0.f, 0.f, 0.f, 0.f};
    float4 accB = {0.f, 0.f, 0.f, 0.f};
    if (init) {
        float4 t = ((const float4*)init)[(size_t)row * 32 + lane];
        accA.x = -t.x; accA.y = -t.y; accA.z = -t.z; accA.w = -t.w;
    }
    int p = rowptr[row];
    const int p1 = rowptr[row + 1];
    for (; p + 7 < p1; p += 8) {
        int2 cv0 = csr[p + 0];
        int2 cv1 = csr[p + 1];
        int2 cv2 = csr[p + 2];
        int2 cv3 = csr[p + 3];
        int2 cv4 = csr[p + 4];
        int2 cv5 = csr[p + 5];
        int2 cv6 = csr[p + 6];
        int2 cv7 = csr[p + 7];
        float4 x0 = X4[(size_t)cv0.x * 32 + lane];
        float4 x1 = X4[(size_t)cv1.x * 32 + lane];
        float4 x2 = X4[(size_t)cv2.x * 32 + lane];
        float4 x3 = X4[(size_t)cv3.x * 32 + lane];
        float4 x4 = X4[(size_t)cv4.x * 32 + lane];
        float4 x5 = X4[(size_t)cv5.x * 32 + lane];
        float4 x6 = X4[(size_t)cv6.x * 32 + lane];
        float4 x7 = X4[(size_t)cv7.x * 32 + lane];
        float v0 = __int_as_float(cv0.y);
        float v1 = __int_as_float(cv1.y);
        float v2 = __int_as_float(cv2.y);
        float v3 = __int_as_float(cv3.y);
        float v4 = __int_as_float(cv4.y);
        float v5 = __int_as_float(cv5.y);
        float v6 = __int_as_float(cv6.y);
        float v7 = __int_as_float(cv7.y);
        accA.x = fmaf(v0, x0.x, accA.x); accA.y = fmaf(v0, x0.y, accA.y);
        accA.z = fmaf(v0, x0.z, accA.z); accA.w = fmaf(v0, x0.w, accA.w);
        accB.x = fmaf(v1, x1.x, accB.x); accB.y = fmaf(v1, x1.y, accB.y);
        accB.z = fmaf(v1, x1.z, accB.z); accB.w = fmaf(v1, x1.w, accB.w);
        accA.x = fmaf(v2, x2.x, accA.x); accA.y = fmaf(v2, x2.y, accA.y);
        accA.z = fmaf(v2, x2.z, accA.z); accA.w = fmaf(v2, x2.w, accA.w);
        accB.x = fmaf(v3, x3.x, accB.x); accB.y = fmaf(v3, x3.y, accB.y);
        accB.z = fmaf(v3, x3.z, accB.z); accB.w = fmaf(v3, x3.w, accB.w);
        accA.x = fmaf(v4, x4.x, accA.x); accA.y = fmaf(v4, x4.y, accA.y);
        accA.z = fmaf(v4, x4.z, accA.z); accA.w = fmaf(v4, x4.w, accA.w);
        accB.x = fmaf(v5, x5.x, accB.x); accB.y = fmaf(v5, x5.y, accB.y);
        accB.z = fmaf(v5, x5.z, accB.z); accB.w = fmaf(v5, x5.w, accB.w);
        accA.x = fmaf(v6, x6.x, accA.x); accA.y = fmaf(v6, x6.y, accA.y);
        accA.z = fmaf(v6, x6.z, accA.z); accA.w = fmaf(v6, x6.w, accA.w);
        accB.x = fmaf(v7, x7.x, accB.x); accB.y = fmaf(v7, x7.y, accB.y);
        accB.z = fmaf(v7, x7.z, accB.z); accB.w = fmaf(v7, x7.w, accB.w);
    }
    for (; p + 3 < p1; p += 4) {
        int2 cv0 = csr[p + 0];
        int2 cv1 = csr[p + 1];
        int2 cv2 = csr[p + 2];
        int2 cv3 = csr[p + 3];
        float4 x0 = X4[(size_t)cv0.x * 32 + lane];
        float4 x1 = X4[(size_t)cv1.x * 32 + lane];
        float4 x2 = X4[(size_t)cv2.x * 32 + lane];
        float4 x3 = X4[(size_t)cv3.x * 32 + lane];
        float v0 = __int_as_float(cv0.y);
        float v1 = __int_as_float(cv1.y);
        float v2 = __int_as_float(cv2.y);
        float v3 = __int_as_float(cv3.y);
        accA.x = fmaf(v0, x0.x, accA.x); accA.y = fmaf(v0, x0.y, accA.y);
        accA.z = fmaf(v0, x0.z, accA.z); accA.w = fmaf(v0, x0.w, accA.w);
        accB.x = fmaf(v1, x1.x, accB.x); accB.y = fmaf(v1, x1.y, accB.y);
        accB.z = fmaf(v1, x1.z, accB.z); accB.w = fmaf(v1, x1.w, accB.w);
        accA.x = fmaf(v2, x2.x, accA.x); accA.y = fmaf(v2, x2.y, accA.y);
        accA.z = fmaf(v2, x2.z, accA.z); accA.w = fmaf(v2, x2.w, accA.w);
        accB.x = fmaf(v3, x3.x, accB.x); accB.y = fmaf(v3, x3.y, accB.y);
        accB.z = fmaf(v3, x3.z, accB.z); accB.w = fmaf(v3, x3.w, accB.w);
    }
    for (; p < p1; ++p) {
        int2 cv = csr[p];
        float v = __int_as_float(cv.y);
        float4 x = X4[(size_t)cv.x * 32 + lane];
        accA.x = fmaf(v, x.x, accA.x);
        accA.y = fmaf(v, x.y, accA.y);
        accA.z = fmaf(v, x.z, accA.z);
        accA.w = fmaf(v, x.w, accA.w);
    }
    float4 acc;
    acc.x = accA.x + accB.x;
    acc.y = accA.y + accB.y;
    acc.z = accA.z + accB.z;
    acc.w = accA.w + accB.w;
    ((float4*)S)[(size_t)row * 32 + lane] = acc;
}

extern "C" void kernel_launch(void* const* d_in, const int* in_sizes, int n_in,
                              void* d_out, int out_size, void* d_ws, size_t ws_size,
                              hipStream_t stream) {
    const float* X     = (const float*)d_in[0];
    const int*   erows = (const int*)d_in[1];
    const int*   ecols = (const int*)d_in[2];
    const float* evals = (const float*)d_in[3];
    const float* W     = (const float*)d_in[4];
    float* out = (float*)d_out;

    const int N = in_sizes[0] / 128;  // 50000
    const int E = in_sizes[1];        // 800000

    // Workspace layout (4-byte elems; csr kept 8B-aligned)
    float* t2     = (float*)d_ws;                      // T2 = 2A.X - X   (N*128)
    float* u2     = t2 + (size_t)N * 128;              // U2 = 2A.T2      (N*128)
    float* W2     = u2 + (size_t)N * 128;              // 128*128
    float* W3     = W2 + 16384;                        // 128*128
    int2*  csr    = (int2*)(W3 + 16384);               // E int2 (8B-aligned)
    int*   rowptr = (int*)(csr + E);                   // N+1
    int*   cursor = rowptr + (N + 1);                  // N+1
    int*   counts = cursor + (N + 1);                  // N
    int*   bsum   = counts + N;                        // <=64

    const int e_blocks = (E + 255) / 256;
    const int nb       = (N + 1023) / 1024;
    const int g_blocks = (int)(((long long)N * 32 + 255) / 256);
    const int d_blocks = (N + 31) / 32;

    // --- W powers (one launch: W2 and W3) ---
    wpow_kernel<<<8, THREADS, 0, stream>>>(W, W2, W3);

    // --- CSR build ---
    hipMemsetAsync(counts, 0, (size_t)N * sizeof(int), stream);
    hist_kernel<<<e_blocks, THREADS, 0, stream>>>(erows, counts, E);
    scanA_kernel<<<nb, 1024, 0, stream>>>(counts, rowptr, bsum, N);
    scanBC_kernel<<<(N + 255) / 256, THREADS, 0, stream>>>(rowptr, cursor, bsum, N, nb);
    scatter_kernel<<<e_blocks, THREADS, 0, stream>>>(erows, ecols, evals, cursor, csr, E);

    // --- Chebyshev chain (reassociated) ---
    // T2 = 2A.X - X
    spmm_gather_kernel<<<g_blocks, THREADS, 0, stream>>>(rowptr, csr, X, X, t2, N);
    // U2 = 2A.T2
    spmm_gather_kernel<<<g_blocks, THREADS, 0, stream>>>(rowptr, csr, t2, nullptr, u2, N);
    // out = U2@W3 - X@W2
    gemm_dual_kernel<<<d_blocks, THREADS, 0, stream>>>(u2, W3, X, W2, out, N);
}

// Round 6
// 254.031 us; speedup vs baseline: 1.5811x; 1.0986x over previous
//
#include <hip/hip_runtime.h>
#include <cstddef>
#include <cstdint>

#define THREADS 256

typedef short bf16x8 __attribute__((ext_vector_type(8)));
typedef float f32x4 __attribute__((ext_vector_type(4)));

#define GLOBAL_AS __attribute__((address_space(1)))
#define LDS_AS    __attribute__((address_space(3)))

// Async global->LDS DMA, 16B per lane (dest must be linear in lane order).
__device__ __forceinline__ void async_copy16(const void* g, void* l) {
    __builtin_amdgcn_global_load_lds((const GLOBAL_AS void*)g, (LDS_AS void*)l, 16, 0, 0);
}

// f32 -> bf16 round-to-nearest-even
__device__ __forceinline__ ushort f2bf(float f) {
    uint32_t u = __float_as_uint(f);
    u = u + 0x7FFFu + ((u >> 16) & 1u);
    return (ushort)(u >> 16);
}
__device__ __forceinline__ float bf2f(ushort h) {
    return __uint_as_float(((uint32_t)h) << 16);
}

// ---------------------------------------------------------------------------
// f32 vector micro-GEMM pieces (used only by wpow for the 128x128 W powers)
// ---------------------------------------------------------------------------
__device__ __forceinline__ void rowfma(float4& acc, const float4 xv,
                                       const float4 w0, const float4 w1,
                                       const float4 w2, const float4 w3) {
    acc.x = fmaf(xv.x, w0.x, acc.x); acc.y = fmaf(xv.x, w0.y, acc.y);
    acc.z = fmaf(xv.x, w0.z, acc.z); acc.w = fmaf(xv.x, w0.w, acc.w);
    acc.x = fmaf(xv.y, w1.x, acc.x); acc.y = fmaf(xv.y, w1.y, acc.y);
    acc.z = fmaf(xv.y, w1.z, acc.z); acc.w = fmaf(xv.y, w1.w, acc.w);
    acc.x = fmaf(xv.z, w2.x, acc.x); acc.y = fmaf(xv.z, w2.y, acc.y);
    acc.z = fmaf(xv.z, w2.z, acc.z); acc.w = fmaf(xv.z, w2.w, acc.w);
    acc.x = fmaf(xv.w, w3.x, acc.x); acc.y = fmaf(xv.w, w3.y, acc.y);
    acc.z = fmaf(xv.w, w3.z, acc.z); acc.w = fmaf(xv.w, w3.w, acc.w);
}

__device__ __forceinline__ void mm32(const float4* Ws4, const float4* Xs4,
                                     int c4, int rb,
                                     float4& a0, float4& a1, float4& a2, float4& a3) {
#pragma unroll 4
    for (int kq = 0; kq < 32; ++kq) {
        float4 w0 = Ws4[(4 * kq + 0) * 32 + c4];
        float4 w1 = Ws4[(4 * kq + 1) * 32 + c4];
        float4 w2 = Ws4[(4 * kq + 2) * 32 + c4];
        float4 w3 = Ws4[(4 * kq + 3) * 32 + c4];
        float4 x0 = Xs4[(rb + 0) * 32 + kq];
        float4 x1 = Xs4[(rb + 1) * 32 + kq];
        float4 x2 = Xs4[(rb + 2) * 32 + kq];
        float4 x3 = Xs4[(rb + 3) * 32 + kq];
        rowfma(a0, x0, w0, w1, w2, w3);
        rowfma(a1, x1, w0, w1, w2, w3);
        rowfma(a2, x2, w0, w1, w2, w3);
        rowfma(a3, x3, w0, w1, w2, w3);
    }
}

// ---------------------------------------------------------------------------
// wpow: blocks 0-3 -> -W^2 slices; blocks 4-7 -> W^3 slices (row-local:
// (W@W)[r,:] = W[r,:]@W). Output stored TRANSPOSED (Wt[col][k]), hi/lo-split
// bf16, XOR-swizzled: u16 idx = col*128 + (k ^ ((col&7)<<3)).  The gemm
// kernel async-stages these linearly into LDS -> swizzled LDS for free.
// ---------------------------------------------------------------------------
__global__ __launch_bounds__(256, 2)
void wpow_kernel(const float* __restrict__ W,
                 ushort* __restrict__ w3t_hi, ushort* __restrict__ w3t_lo,
                 ushort* __restrict__ nw2t_hi, ushort* __restrict__ nw2t_lo) {
    __shared__ float4 Ws4[128 * 32];  // 64KB: full W
    __shared__ float4 Xs4[32 * 32];   // 16KB: 32-row operand slice
    const int tid = threadIdx.x;
    const int row0 = (blockIdx.x & 3) * 32;
    const bool is3 = blockIdx.x >= 4;
    const float4* __restrict__ W4 = (const float4*)W;

#pragma unroll
    for (int i = 0; i < 16; ++i) Ws4[tid + i * 256] = W4[tid + i * 256];
#pragma unroll
    for (int i = 0; i < 4; ++i) {
        int li = tid + i * 256;
        Xs4[li] = W4[(size_t)(row0 + (li >> 5)) * 32 + (li & 31)];
    }
    __syncthreads();

    const int c4 = tid & 31;
    const int rb = (tid >> 5) * 4;
    float4 a0 = {0.f, 0.f, 0.f, 0.f};
    float4 a1 = {0.f, 0.f, 0.f, 0.f};
    float4 a2 = {0.f, 0.f, 0.f, 0.f};
    float4 a3 = {0.f, 0.f, 0.f, 0.f};
    mm32(Ws4, Xs4, c4, rb, a0, a1, a2, a3);

    if (is3) {  // second multiply: S2 = S1 @ W
        __syncthreads();
        Xs4[(rb + 0) * 32 + c4] = a0;
        Xs4[(rb + 1) * 32 + c4] = a1;
        Xs4[(rb + 2) * 32 + c4] = a2;
        Xs4[(rb + 3) * 32 + c4] = a3;
        __syncthreads();
        a0 = {0.f, 0.f, 0.f, 0.f};
        a1 = {0.f, 0.f, 0.f, 0.f};
        a2 = {0.f, 0.f, 0.f, 0.f};
        a3 = {0.f, 0.f, 0.f, 0.f};
        mm32(Ws4, Xs4, c4, rb, a0, a1, a2, a3);
    }

    ushort* __restrict__ dh = is3 ? w3t_hi : nw2t_hi;
    ushort* __restrict__ dl = is3 ? w3t_lo : nw2t_lo;
    const float sgn = is3 ? 1.0f : -1.0f;
    const int r = row0 + rb;
#pragma unroll
    for (int i = 0; i < 4; ++i) {
        float4 a = (i == 0) ? a0 : (i == 1) ? a1 : (i == 2) ? a2 : a3;
        const int k = r + i;  // k-index (row of W^p)
#pragma unroll
        for (int e = 0; e < 4; ++e) {
            float v = ((e == 0) ? a.x : (e == 1) ? a.y : (e == 2) ? a.z : a.w) * sgn;
            int c = c4 * 4 + e;
            int idx = c * 128 + (k ^ ((c & 7) << 3));
            ushort h = f2bf(v);
            dh[idx] = h;
            dl[idx] = f2bf(v - bf2f(h));
        }
    }
}

// ---------------------------------------------------------------------------
// Dual GEMM via bf16 hi/lo-split MFMA: out = A1 @ B1 + A2 @ B2 where the Bt
// arrays hold (W3) and (-W2) transposed/split/swizzled.  32 rows per block,
// 4 waves: wave w owns M-tile (w&1), N-tiles (w>>1)*4..+3.
// C ~= Ah@Bh + Al@Bh + Ah@Bl  (AlBl dropped, ~2^-18 rel).
// ---------------------------------------------------------------------------
__global__ __launch_bounds__(256, 2)
void gemm_dual_mfma(const float* __restrict__ A1, const ushort* __restrict__ B1h,
                    const ushort* __restrict__ B1l,
                    const float* __restrict__ A2, const ushort* __restrict__ B2h,
                    const ushort* __restrict__ B2l,
                    float* __restrict__ out, int N) {
    __shared__ ushort WtHi[16384];  // 32KB  Wt[col][k] hi, swizzled
    __shared__ ushort WtLo[16384];  // 32KB
    __shared__ ushort XsHi[4096];   // 8KB   Xs[row][k] hi, swizzled
    __shared__ ushort XsLo[4096];   // 8KB
    const int tid = threadIdx.x;
    const int row0 = blockIdx.x * 32;
    const int l = tid & 63, w = tid >> 6;
    const int mt = w & 1, ntb = (w >> 1) * 4;
    const int fr = l & 15, fh = l >> 4;

    f32x4 acc[4];
#pragma unroll
    for (int nt = 0; nt < 4; ++nt) acc[nt] = (f32x4){0.f, 0.f, 0.f, 0.f};

    for (int pass = 0; pass < 2; ++pass) {
        const float* __restrict__ Asrc = pass ? A2 : A1;
        const ushort* __restrict__ Bh = pass ? B2h : B1h;
        const ushort* __restrict__ Bl = pass ? B2l : B1l;
        if (pass) __syncthreads();  // pass-0 readers done before restage

        // stage Wt hi/lo (64KB) via async DMA; global already swizzled
#pragma unroll
        for (int i = 0; i < 8; ++i) {
            async_copy16(Bh + tid * 8 + i * 2048, WtHi + tid * 8 + i * 2048);
            async_copy16(Bl + tid * 8 + i * 2048, WtLo + tid * 8 + i * 2048);
        }

        // stage Xs: thread -> (row = tid>>3, 16 k's at (tid&7)*16); convert
        {
            const int row = tid >> 3, kb = (tid & 7) * 16;
            int gr = row0 + row;
            if (gr >= N) gr = N - 1;  // clamped rows never stored
            const float4* __restrict__ ap =
                (const float4*)(Asrc + (size_t)gr * 128) + (kb >> 2);
            float4 v0 = ap[0], v1 = ap[1], v2 = ap[2], v3 = ap[3];
            float f[16] = {v0.x, v0.y, v0.z, v0.w, v1.x, v1.y, v1.z, v1.w,
                           v2.x, v2.y, v2.z, v2.w, v3.x, v3.y, v3.z, v3.w};
            ushort hi[16], lo[16];
#pragma unroll
            for (int i = 0; i < 16; ++i) {
                hi[i] = f2bf(f[i]);
                lo[i] = f2bf(f[i] - bf2f(hi[i]));
            }
#pragma unroll
            for (int g = 0; g < 2; ++g) {
                int idx = row * 128 + ((kb + 8 * g) ^ ((row & 7) << 3));
                bf16x8 vh, vl;
#pragma unroll
                for (int j = 0; j < 8; ++j) {
                    vh[j] = (short)hi[8 * g + j];
                    vl[j] = (short)lo[8 * g + j];
                }
                *(bf16x8*)&XsHi[idx] = vh;
                *(bf16x8*)&XsLo[idx] = vl;
            }
        }
        __syncthreads();  // drains async vmcnt + ds writes

        // MFMA: 4 ksteps x 4 N-tiles x 3 (hi/lo split)
#pragma unroll
        for (int ks = 0; ks < 4; ++ks) {
            const int arow = mt * 16 + fr;
            const int aoff = arow * 128 + ((ks * 32 + fh * 8) ^ ((arow & 7) << 3));
            bf16x8 ah = *(const bf16x8*)&XsHi[aoff];
            bf16x8 al = *(const bf16x8*)&XsLo[aoff];
#pragma unroll
            for (int nt = 0; nt < 4; ++nt) {
                const int brow = (ntb + nt) * 16 + fr;
                const int boff = brow * 128 + ((ks * 32 + fh * 8) ^ ((brow & 7) << 3));
                bf16x8 bh = *(const bf16x8*)&WtHi[boff];
                bf16x8 bl = *(const bf16x8*)&WtLo[boff];
                acc[nt] = __builtin_amdgcn_mfma_f32_16x16x32_bf16(ah, bh, acc[nt], 0, 0, 0);
                acc[nt] = __builtin_amdgcn_mfma_f32_16x16x32_bf16(al, bh, acc[nt], 0, 0, 0);
                acc[nt] = __builtin_amdgcn_mfma_f32_16x16x32_bf16(ah, bl, acc[nt], 0, 0, 0);
            }
        }
    }

    // epilogue: verified C/D map: col = lane&15, row = (lane>>4)*4 + reg
#pragma unroll
    for (int nt = 0; nt < 4; ++nt) {
        const int col = (ntb + nt) * 16 + fr;
#pragma unroll
        for (int i = 0; i < 4; ++i) {
            const int rr = row0 + mt * 16 + fh * 4 + i;
            if (rr < N) out[(size_t)rr * 128 + col] = acc[nt][i];
        }
    }
}

// ---------------------------------------------------------------------------
// CSR build: histogram -> scanA (multi-block) -> scanBC (fused) -> scatter
// ---------------------------------------------------------------------------
__global__ void hist_kernel(const int* __restrict__ erows, int* __restrict__ counts, int E) {
    int e = blockIdx.x * blockDim.x + threadIdx.x;
    if (e < E) atomicAdd(&counts[erows[e]], 1);
}

__global__ __launch_bounds__(1024)
void scanA_kernel(const int* __restrict__ counts, int* __restrict__ rowptr,
                  int* __restrict__ blocksum, int n) {
    __shared__ int buf[1024];
    const int tid = threadIdx.x;
    const int i = blockIdx.x * 1024 + tid;
    int v = (i < n) ? counts[i] : 0;
    buf[tid] = v;
    __syncthreads();
#pragma unroll
    for (int off = 1; off < 1024; off <<= 1) {
        int t = (tid >= off) ? buf[tid - off] : 0;
        __syncthreads();
        buf[tid] += t;
        __syncthreads();
    }
    if (i < n) rowptr[i + 1] = buf[tid];
    if (tid == 1023) blocksum[blockIdx.x] = buf[1023];
}

__global__ void scanBC_kernel(int* __restrict__ rowptr, int* __restrict__ cursor,
                              const int* __restrict__ blocksum, int n, int nb) {
    __shared__ int off[64];
    const int tid = threadIdx.x;
    if (tid < 64) {
        int v = (tid < nb) ? blocksum[tid] : 0;
        int orig = v;
#pragma unroll
        for (int o = 1; o < 64; o <<= 1) {
            int t = __shfl_up(v, o);
            if (tid >= o) v += t;
        }
        off[tid] = v - orig;  // exclusive prefix
    }
    __syncthreads();
    int i = blockIdx.x * blockDim.x + tid;
    if (i < n) {
        int v = rowptr[i + 1] + off[i >> 10];
        rowptr[i + 1] = v;
        cursor[i + 1] = v;
    }
    if (i == 0) { rowptr[0] = 0; cursor[0] = 0; }
}

__global__ void scatter_kernel(const int* __restrict__ erows, const int* __restrict__ ecols,
                               const float* __restrict__ evals, int* __restrict__ cursor,
                               int2* __restrict__ csr, int E) {
    int e = blockIdx.x * blockDim.x + threadIdx.x;
    if (e < E) {
        int r = erows[e];
        int pos = atomicAdd(&cursor[r], 1);
        int2 p;
        p.x = ecols[e];
        p.y = __float_as_int(2.0f * evals[e]);
        csr[pos] = p;
    }
}

// ---------------------------------------------------------------------------
// Gather SpMM: S[row] = sum_e 2*val_e * X[col_e]  (- init[row] if init)
// ---------------------------------------------------------------------------
__global__ __launch_bounds__(256, 8)
void spmm_gather_kernel(const int* __restrict__ rowptr, const int2* __restrict__ csr,
                        const float* __restrict__ X, const float* __restrict__ init,
                        float* __restrict__ S, int N) {
    long long idx = (long long)blockIdx.x * blockDim.x + threadIdx.x;
    int row = (int)(idx >> 5);
    if (row >= N) return;
    int lane = (int)(idx & 31);
    const float4* __restrict__ X4 = (const float4*)X;
    float4 accA = {0.f, 0.f, 0.f, 0.f};
    float4 accB = {0.f, 0.f, 0.f, 0.f};
    if (init) {
        float4 t = ((const float4*)init)[(size_t)row * 32 + lane];
        accA.x = -t.x; accA.y = -t.y; accA.z = -t.z; accA.w = -t.w;
    }
    int p = rowptr[row];
    const int p1 = rowptr[row + 1];
    for (; p + 7 < p1; p += 8) {
        int2 cv0 = csr[p + 0];
        int2 cv1 = csr[p + 1];
        int2 cv2 = csr[p + 2];
        int2 cv3 = csr[p + 3];
        int2 cv4 = csr[p + 4];
        int2 cv5 = csr[p + 5];
        int2 cv6 = csr[p + 6];
        int2 cv7 = csr[p + 7];
        float4 x0 = X4[(size_t)cv0.x * 32 + lane];
        float4 x1 = X4[(size_t)cv1.x * 32 + lane];
        float4 x2 = X4[(size_t)cv2.x * 32 + lane];
        float4 x3 = X4[(size_t)cv3.x * 32 + lane];
        float4 x4 = X4[(size_t)cv4.x * 32 + lane];
        float4 x5 = X4[(size_t)cv5.x * 32 + lane];
        float4 x6 = X4[(size_t)cv6.x * 32 + lane];
        float4 x7 = X4[(size_t)cv7.x * 32 + lane];
        float v0 = __int_as_float(cv0.y);
        float v1 = __int_as_float(cv1.y);
        float v2 = __int_as_float(cv2.y);
        float v3 = __int_as_float(cv3.y);
        float v4 = __int_as_float(cv4.y);
        float v5 = __int_as_float(cv5.y);
        float v6 = __int_as_float(cv6.y);
        float v7 = __int_as_float(cv7.y);
        accA.x = fmaf(v0, x0.x, accA.x); accA.y = fmaf(v0, x0.y, accA.y);
        accA.z = fmaf(v0, x0.z, accA.z); accA.w = fmaf(v0, x0.w, accA.w);
        accB.x = fmaf(v1, x1.x, accB.x); accB.y = fmaf(v1, x1.y, accB.y);
        accB.z = fmaf(v1, x1.z, accB.z); accB.w = fmaf(v1, x1.w, accB.w);
        accA.x = fmaf(v2, x2.x, accA.x); accA.y = fmaf(v2, x2.y, accA.y);
        accA.z = fmaf(v2, x2.z, accA.z); accA.w = fmaf(v2, x2.w, accA.w);
        accB.x = fmaf(v3, x3.x, accB.x); accB.y = fmaf(v3, x3.y, accB.y);
        accB.z = fmaf(v3, x3.z, accB.z); accB.w = fmaf(v3, x3.w, accB.w);
        accA.x = fmaf(v4, x4.x, accA.x); accA.y = fmaf(v4, x4.y, accA.y);
        accA.z = fmaf(v4, x4.z, accA.z); accA.w = fmaf(v4, x4.w, accA.w);
        accB.x = fmaf(v5, x5.x, accB.x); accB.y = fmaf(v5, x5.y, accB.y);
        accB.z = fmaf(v5, x5.z, accB.z); accB.w = fmaf(v5, x5.w, accB.w);
        accA.x = fmaf(v6, x6.x, accA.x); accA.y = fmaf(v6, x6.y, accA.y);
        accA.z = fmaf(v6, x6.z, accA.z); accA.w = fmaf(v6, x6.w, accA.w);
        accB.x = fmaf(v7, x7.x, accB.x); accB.y = fmaf(v7, x7.y, accB.y);
        accB.z = fmaf(v7, x7.z, accB.z); accB.w = fmaf(v7, x7.w, accB.w);
    }
    for (; p + 3 < p1; p += 4) {
        int2 cv0 = csr[p + 0];
        int2 cv1 = csr[p + 1];
        int2 cv2 = csr[p + 2];
        int2 cv3 = csr[p + 3];
        float4 x0 = X4[(size_t)cv0.x * 32 + lane];
        float4 x1 = X4[(size_t)cv1.x * 32 + lane];
        float4 x2 = X4[(size_t)cv2.x * 32 + lane];
        float4 x3 = X4[(size_t)cv3.x * 32 + lane];
        float v0 = __int_as_float(cv0.y);
        float v1 = __int_as_float(cv1.y);
        float v2 = __int_as_float(cv2.y);
        float v3 = __int_as_float(cv3.y);
        accA.x = fmaf(v0, x0.x, accA.x); accA.y = fmaf(v0, x0.y, accA.y);
        accA.z = fmaf(v0, x0.z, accA.z); accA.w = fmaf(v0, x0.w, accA.w);
        accB.x = fmaf(v1, x1.x, accB.x); accB.y = fmaf(v1, x1.y, accB.y);
        accB.z = fmaf(v1, x1.z, accB.z); accB.w = fmaf(v1, x1.w, accB.w);
        accA.x = fmaf(v2, x2.x, accA.x); accA.y = fmaf(v2, x2.y, accA.y);
        accA.z = fmaf(v2, x2.z, accA.z); accA.w = fmaf(v2, x2.w, accA.w);
        accB.x = fmaf(v3, x3.x, accB.x); accB.y = fmaf(v3, x3.y, accB.y);
        accB.z = fmaf(v3, x3.z, accB.z); accB.w = fmaf(v3, x3.w, accB.w);
    }
    for (; p < p1; ++p) {
        int2 cv = csr[p];
        float v = __int_as_float(cv.y);
        float4 x = X4[(size_t)cv.x * 32 + lane];
        accA.x = fmaf(v, x.x, accA.x);
        accA.y = fmaf(v, x.y, accA.y);
        accA.z = fmaf(v, x.z, accA.z);
        accA.w = fmaf(v, x.w, accA.w);
    }
    float4 acc;
    acc.x = accA.x + accB.x;
    acc.y = accA.y + accB.y;
    acc.z = accA.z + accB.z;
    acc.w = accA.w + accB.w;
    ((float4*)S)[(size_t)row * 32 + lane] = acc;
}

extern "C" void kernel_launch(void* const* d_in, const int* in_sizes, int n_in,
                              void* d_out, int out_size, void* d_ws, size_t ws_size,
                              hipStream_t stream) {
    const float* X     = (const float*)d_in[0];
    const int*   erows = (const int*)d_in[1];
    const int*   ecols = (const int*)d_in[2];
    const float* evals = (const float*)d_in[3];
    const float* W     = (const float*)d_in[4];
    float* out = (float*)d_out;

    const int N = in_sizes[0] / 128;  // 50000
    const int E = in_sizes[1];        // 800000

    // Workspace layout
    float*  t2      = (float*)d_ws;                  // T2 = 2A.X - X   (N*128)
    float*  u2      = t2 + (size_t)N * 128;          // U2 = 2A.T2      (N*128)
    ushort* wtab    = (ushort*)(u2 + (size_t)N * 128);
    ushort* w3t_hi  = wtab;                          // 16384 each, bf16
    ushort* w3t_lo  = wtab + 16384;
    ushort* nw2t_hi = wtab + 32768;
    ushort* nw2t_lo = wtab + 49152;
    int2*   csr     = (int2*)(wtab + 65536);         // E int2 (8B-aligned)
    int*    rowptr  = (int*)(csr + E);               // N+1
    int*    cursor  = rowptr + (N + 1);              // N+1
    int*    counts  = cursor + (N + 1);              // N
    int*    bsum    = counts + N;                    // <=64

    const int e_blocks = (E + 255) / 256;
    const int nb       = (N + 1023) / 1024;
    const int g_blocks = (int)(((long long)N * 32 + 255) / 256);
    const int d_blocks = (N + 31) / 32;

    // --- W powers -> transposed/split/swizzled bf16 tables (one launch) ---
    wpow_kernel<<<8, THREADS, 0, stream>>>(W, w3t_hi, w3t_lo, nw2t_hi, nw2t_lo);

    // --- CSR build ---
    hipMemsetAsync(counts, 0, (size_t)N * sizeof(int), stream);
    hist_kernel<<<e_blocks, THREADS, 0, stream>>>(erows, counts, E);
    scanA_kernel<<<nb, 1024, 0, stream>>>(counts, rowptr, bsum, N);
    scanBC_kernel<<<(N + 255) / 256, THREADS, 0, stream>>>(rowptr, cursor, bsum, N, nb);
    scatter_kernel<<<e_blocks, THREADS, 0, stream>>>(erows, ecols, evals, cursor, csr, E);

    // --- Chebyshev chain (reassociated) ---
    // T2 = 2A.X - X
    spmm_gather_kernel<<<g_blocks, THREADS, 0, stream>>>(rowptr, csr, X, X, t2, N);
    // U2 = 2A.T2
    spmm_gather_kernel<<<g_blocks, THREADS, 0, stream>>>(rowptr, csr, t2, nullptr, u2, N);
    // out = U2@W3 - X@W2   (second term via pre-negated W2 tables)
    gemm_dual_mfma<<<d_blocks, THREADS, 0, stream>>>(u2, w3t_hi, w3t_lo,
                                                     X, nw2t_hi, nw2t_lo, out, N);
}